// Round 18
// baseline (64.137 us; speedup 1.0000x reference)
//
#include <hip/hip_runtime.h>

#define FDIM   251
#define NFILT  80
#define KPAD   256        // K padded to 8 chunks of 32 (zeros past 250)
#define T_IN   64000
#define T_OUT  63750      // 64000 - 251 + 1
#define NCHUNK 512        // output positions per block; compute wave owns 128
#define NXB    125        // t-chunks
#define NFT    5          // filter tiles (16 filters each) - looped IN-block
#define CPYLEN 392        // dwords per shifted copy; covers max read idx 379 (r12-validated)
#define XSTOT  (8 * CPYLEN)   // 12.25 KB
#define BUFSTR 514        // out-tile row stride (dwords): even (b64-aligned), delta%32=2 -> ~2-way banks
#define BUFSZ  (16 * BUFSTR)  // one 16x512 tile = 32.1 KB; x2 buffers

typedef short bf16x8 __attribute__((ext_vector_type(8)));
typedef float f32x4  __attribute__((ext_vector_type(4)));

__device__ __forceinline__ unsigned short f2bf(float f) {
  unsigned int u = __float_as_uint(f);
  unsigned int r = (u + 0x7fffu + ((u >> 16) & 1u)) >> 16;   // RNE
  return (unsigned short)r;
}
__device__ __forceinline__ unsigned int packbf(float a, float b) {
  return (unsigned int)f2bf(a) | ((unsigned int)f2bf(b) << 16);
}

// ---------------------------------------------------------------------------
// Filter construction (validated rounds 1-17). Emits bf16 W[80][256].
// ---------------------------------------------------------------------------
__device__ __forceinline__ void norm_pm1_shared(float* a, float* scratch, int tid) {
  float v  = (tid < FDIM) ? a[tid] : 0.f;
  float mn = (tid < FDIM) ? v : 1e30f;
  float mx = (tid < FDIM) ? v : -1e30f;
  #pragma unroll
  for (int o = 32; o > 0; o >>= 1) {
    mn = fminf(mn, __shfl_down(mn, o));
    mx = fmaxf(mx, __shfl_down(mx, o));
  }
  const int wid = tid >> 6;
  if ((tid & 63) == 0) { scratch[wid] = mn; scratch[4 + wid] = mx; }
  __syncthreads();
  if (tid == 0) {
    scratch[0] = fminf(fminf(scratch[0], scratch[1]), fminf(scratch[2], scratch[3]));
    scratch[4] = fmaxf(fmaxf(scratch[4], scratch[5]), fmaxf(scratch[6], scratch[7]));
  }
  __syncthreads();
  const float gmn = scratch[0], gmx = scratch[4];
  const float nv = 2.f * (v - gmn) / (gmx - gmn + 1e-6f) - 1.f;
  __syncthreads();
  float s = (tid < FDIM) ? nv : 0.f;
  #pragma unroll
  for (int o = 32; o > 0; o >>= 1) s += __shfl_down(s, o);
  if ((tid & 63) == 0) scratch[wid] = s;
  __syncthreads();
  if (tid == 0) scratch[0] = (scratch[0] + scratch[1] + scratch[2] + scratch[3]) / 251.f;
  __syncthreads();
  const float mean = scratch[0];
  if (tid < FDIM) a[tid] = nv - mean;
  __syncthreads();
}

__global__ __launch_bounds__(256) void build_filters_kernel(
    const float* __restrict__ nf1, const float* __restrict__ nf2,
    const float* __restrict__ nf3, const float* __restrict__ nf4,
    const float* __restrict__ amp1, const float* __restrict__ amp2,
    unsigned short* __restrict__ Wbf) {
  __shared__ float ir1[FDIM], ir2[FDIM], casc[FDIM];
  __shared__ float scratch[8];
  const int f = blockIdx.x, tid = threadIdx.x;
  const float FS  = 16000.f;
  const float MF  = 50.f / 16000.f;
  const float PIF = 3.14159265358979323846f;
  const float TPI = 6.28318530717958647692f;

  const float f1 = fminf(fmaxf(fabsf(nf1[f]) + MF, 0.f), 0.5f);
  const float f2 = fminf(fmaxf(f1 + fabsf(nf2[f] - f1) + MF, 0.f), 0.5f);
  const float f3 = fminf(fmaxf(fabsf(nf3[f]) + MF, 0.f), 0.5f);
  const float f4 = fminf(fmaxf(f3 + fabsf(nf4[f] - f3) + MF, 0.f), 0.5f);
  const float a1 = fabsf(amp1[f]);
  const float a2 = fabsf(amp2[f]);

  if (tid < FDIM) {
    const float t = (float)(tid + 1) / FS;
    {
      const float fcs = 0.5f * (f1 + f2) * FS, bws = (f2 - f1) * FS;
      const float pb = PIF * bws;
      ir1[tid] = a1 * expf(-2.f * pb * pb * (t * t)) * cosf(TPI * fcs * t);
    }
    {
      const float fcs = 0.5f * (f3 + f4) * FS, bws = (f4 - f3) * FS;
      const float pb = PIF * bws;
      ir2[tid] = a2 * expf(-2.f * pb * pb * (t * t)) * cosf(TPI * fcs * t);
    }
  }
  __syncthreads();
  norm_pm1_shared(ir1, scratch, tid);
  norm_pm1_shared(ir2, scratch, tid);

  if (tid < FDIM) {
    const int i = tid;
    const int plo = (i - 125 > 0) ? (i - 125) : 0;
    const int phi = (i + 125 < 250) ? (i + 125) : 250;
    float s = 0.f;
    for (int p = plo; p <= phi; ++p) s += ir1[p] * ir2[p + 125 - i];
    casc[i] = s;
  }
  __syncthreads();
  norm_pm1_shared(casc, scratch, tid);

  if (tid < KPAD) {
    float v = 0.f;
    if (tid < FDIM) {
      const float win = 0.54f - 0.46f * cosf(TPI * ((float)tid / 250.f));
      v = casc[tid] * win;
    }
    Wbf[(size_t)f * KPAD + tid] = f2bf(v);
  }
}

// ---------------------------------------------------------------------------
// Implicit-GEMM conv, round-18: WAVE SPECIALIZATION (producer/consumer).
// Diagnosis (r15/r16/r17): store cost is additive because the per-CU write
// queue drains at ~22 GB/s; when full, EVERY wave parks at its next store
// and can't issue MFMA -> compute time + drain time sum. r17 proved the
// serialization is not in the wave's wait instructions.
// Fix: block = 512 threads. Waves 0-3 COMPUTE (r7-validated fragment path;
// zero global stores -> never park on the write queue). Waves 4-7 WRITE
// (absorb all queue stalls). Per ft phase: compute deposits its 16x512
// f32 tile into double-buffered LDS (stride 514 -> ~2-way banks); writers
// stream the PREVIOUS phase's tile as 512B-contiguous float2 runs. One
// __syncthreads per phase; drain of phase p-1 overlaps compute of phase p.
// Wall/CU -> max(compute, drain) instead of sum.
// LDS: xs 12.25 + 2x32.1 = 78.3 KB -> 2 blocks/CU; launch_bounds(512,4)
// -> 128-VGPR cap (compute path ~112, r11-verified no-spill territory).
// Same products, same chunk order -> bit-identical output (absmax 0.125).
// ---------------------------------------------------------------------------
__global__ __launch_bounds__(512, 4) void conv_mfma_kernel(
    const float* __restrict__ xin, const unsigned short* __restrict__ Wbf,
    float* __restrict__ outp) {
  __shared__ __align__(16) unsigned int xs[XSTOT];
  __shared__ __align__(16) float obuf[2 * BUFSZ];
  const int tid = threadIdx.x;
  const int n0  = blockIdx.x * NCHUNK;
  const int b   = blockIdx.y;
  const int l   = tid & 63, wid = tid >> 6;
  const int m   = l & 15, h = l >> 4;

  // ---- stage x ONCE as 8 shifted bf16-pair copies (all 8 waves) ----
  const float* xg = xin + (size_t)b * T_IN;
  for (int i = tid; i < CPYLEN - 4; i += 512) {
    float e[10];
    #pragma unroll
    for (int q = 0; q < 10; ++q) {
      const int g = n0 + 2 * i + q;
      e[q] = (g < T_IN) ? xg[g] : 0.f;
    }
    #pragma unroll
    for (int j = 0; j < 8; ++j)
      xs[j * CPYLEN + i] = packbf(e[j], e[j + 1]);
  }
  __syncthreads();

  // lane-constant B(x) addressing (validated r4-r17)
  const unsigned int* psrc = xs + (m & 7) * CPYLEN;
  const int lane_q = h + (m >> 3);
  const short* Wp = (const short*)Wbf;
  const int w   = wid & 3;            // compute wave index
  const int tw0 = w * 128;            // compute wave's t base within chunk
  const int wid2 = wid - 4;           // writer wave index

  #pragma unroll 1
  for (int p = 0; p < NFT + 1; ++p) {
    if (wid < 4) {
      if (p < NFT) {                  // ---- COMPUTE phase ft = p ----
        const int ft = p;
        bf16x8 afr[8];                // W loads: own vmcnt only (no stores)
        #pragma unroll
        for (int c = 0; c < 8; ++c)
          afr[c] = *(const bf16x8*)(Wp + (ft * 16 + m) * KPAD + c * 32 + h * 8);

        float* buf = &obuf[(p & 1) * BUFSZ];
        for (int jp = 0; jp < 4; ++jp) {
          const int qA = ((tw0 + jp * 32) >> 3) + lane_q;
          f32x4 accA = (f32x4){0.f, 0.f, 0.f, 0.f};
          f32x4 accB = (f32x4){0.f, 0.f, 0.f, 0.f};
          #pragma unroll
          for (int c = 0; c < 8; ++c) {
            const bf16x8 xa = *(const bf16x8*)(psrc + 4 * (qA + 4 * c));
            const bf16x8 xb = *(const bf16x8*)(psrc + 4 * (qA + 2 + 4 * c));
            accA = __builtin_amdgcn_mfma_f32_16x16x32_bf16(afr[c], xa, accA, 0, 0, 0);
            accB = __builtin_amdgcn_mfma_f32_16x16x32_bf16(afr[c], xb, accB, 0, 0, 0);
          }
          const int tA = tw0 + jp * 32 + m;   // local t, D col = m
          #pragma unroll
          for (int r = 0; r < 4; ++r) {       // D row = 4h + r
            buf[(4 * h + r) * BUFSTR + tA]      = accA[r];
            buf[(4 * h + r) * BUFSTR + tA + 16] = accB[r];
          }
        }
      }
    } else {
      if (p >= 1) {                   // ---- WRITE phase ft = p-1 ----
        const int ft = p - 1;
        const float* buf = &obuf[((p - 1) & 1) * BUFSZ];
        #pragma unroll
        for (int q = 0; q < 4; ++q) {
          const int row = 4 * wid2 + q;
          const size_t rb = ((size_t)b * NFILT + ft * 16 + row) * T_OUT + n0;
          #pragma unroll
          for (int seg = 0; seg < 4; ++seg) {  // 4 x 512B contiguous per row
            const int off = seg * 128 + 2 * l;
            if (n0 + off < T_OUT) {            // off even, T_OUT even -> pair safe
              const float2 v = *(const float2*)&buf[row * BUFSTR + off];
              *(float2*)&outp[rb + off] = v;
            }
          }
        }
      }
    }
    __syncthreads();   // phase boundary: buf[p&1] full, buf[(p-1)&1] drained-issued
  }
}

// ---------------------------------------------------------------------------
extern "C" void kernel_launch(void* const* d_in, const int* in_sizes, int n_in,
                              void* d_out, int out_size, void* d_ws, size_t ws_size,
                              hipStream_t stream) {
  const float* x    = (const float*)d_in[0];
  const float* nf1  = (const float*)d_in[1];
  const float* nf2  = (const float*)d_in[2];
  const float* nf3  = (const float*)d_in[3];
  const float* nf4  = (const float*)d_in[4];
  const float* amp1 = (const float*)d_in[5];
  const float* amp2 = (const float*)d_in[6];
  unsigned short* Wbf = (unsigned short*)d_ws;   // 80*256*2 = 40 KB scratch
  float* out = (float*)d_out;

  build_filters_kernel<<<NFILT, 256, 0, stream>>>(nf1, nf2, nf3, nf4, amp1, amp2, Wbf);

  dim3 grid(NXB, 8);   // 125 x 8 = 1000 blocks; ft pipelined in-block
  conv_mfma_kernel<<<grid, 512, 0, stream>>>(x, Wbf, out);
}